// Round 7
// baseline (108.377 us; speedup 1.0000x reference)
//
#include <hip/hip_runtime.h>
#include <cstdint>
#include <cstddef>

#define NN 8192
#define INF 512
#define OUTF 64
#define ALPHA 0.2f
#define NSPLIT 16
#define JSPLIT (NN / NSPLIT)   // 512
#define NW32 (NN / 32)         // 256 mask words per row
#define GEMM_BLOCKS 512

typedef short bf16x8 __attribute__((ext_vector_type(8)));
typedef float f32x4 __attribute__((ext_vector_type(4)));

static __device__ inline unsigned short f2bf(float f) {
    unsigned u = __builtin_bit_cast(unsigned, f);
    unsigned r = (u + 0x7FFFu + ((u >> 16) & 1u)) >> 16;
    return (unsigned short)r;
}

// ---------------------------------------------------------------------------
// Kernel 01 (fused):
//   blocks 0..511: Wh GEMM (LDS-free, wave-uniform x rows). Epilogue writes
//     Asw (MFMA-A-swizzled bf16 Wh), U=exp(0.8 s1), E2p=exp(s2), E2n=exp(.2 s2).
//     (The row factor exp(0.2 s1) cancels in softmax and is dropped.)
//   blocks 512..8703: adj -> TRANSPOSED bitmask maskT[jword][i] via LDS
//     transpose (8 rows x 1024 js per block, XOR-swizzled to the 8-way floor).
// ---------------------------------------------------------------------------
__global__ __launch_bounds__(256) void k01_fused(
    const float* __restrict__ x, const int* __restrict__ adj,
    const float* __restrict__ W, const float* __restrict__ a,
    unsigned short* __restrict__ Asw, float* __restrict__ U,
    float* __restrict__ E2p, float* __restrict__ E2n,
    unsigned* __restrict__ maskT)
{
    __shared__ int4 lds4[8][256];   // 32 KB (mask path only)
    const int tid = threadIdx.x;

    if (blockIdx.x >= GEMM_BLOCKS) {
        // ---------------- mask path: 8 rows x 1024 js, transposed out -------
        const int mb   = blockIdx.x - GEMM_BLOCKS;   // 0..8191
        const int r0   = (mb & 1023) * 8;
        const int jseg = mb >> 10;                   // 0..7
        const int* abase = adj + (size_t)r0 * NN + jseg * 1024;

        // phase 1: row k, int4-col tid (4 KB contiguous per instr), swizzled
        #pragma unroll
        for (int k = 0; k < 8; ++k) {
            int4 v = *(const int4*)(abase + (size_t)k * NN + tid * 4);
            lds4[k][tid ^ (k & 7)] = v;
        }
        __syncthreads();

        // phase 2: thread (wc, r) packs word for (row r0+r, js jseg*1024+wc*32..)
        const int wc = tid >> 3;    // 0..31
        const int r  = tid & 7;
        unsigned m = 0;
        #pragma unroll
        for (int k4 = 0; k4 < 8; ++k4) {
            int4 v = lds4[r][(wc * 8 + k4) ^ r];
            m |= (v.x != 0 ? 1u : 0u) << (4 * k4);
            m |= (v.y != 0 ? 1u : 0u) << (4 * k4 + 1);
            m |= (v.z != 0 ? 1u : 0u) << (4 * k4 + 2);
            m |= (v.w != 0 ? 1u : 0u) << (4 * k4 + 3);
        }
        maskT[(size_t)(jseg * 32 + wc) * NN + r0 + r] = m;
        return;
    }

    // ---------------- GEMM path: 16 rows of Wh per block ----------------
    const int i0 = blockIdx.x * 16;
    const int w  = __builtin_amdgcn_readfirstlane(tid >> 6);
    const int c  = tid & 63;

    const float* xr = x + (size_t)(i0 + 4 * w) * INF;
    const float* Wc = W + c;
    float acc[4] = {0.f, 0.f, 0.f, 0.f};

    #pragma unroll 4
    for (int kk = 0; kk < 128; ++kk) {
        const float4 x0 = *(const float4*)(xr + 0 * INF + kk * 4);
        const float4 x1 = *(const float4*)(xr + 1 * INF + kk * 4);
        const float4 x2 = *(const float4*)(xr + 2 * INF + kk * 4);
        const float4 x3 = *(const float4*)(xr + 3 * INF + kk * 4);
        const float w0 = Wc[(kk * 4 + 0) * OUTF];
        const float w1 = Wc[(kk * 4 + 1) * OUTF];
        const float w2 = Wc[(kk * 4 + 2) * OUTF];
        const float w3 = Wc[(kk * 4 + 3) * OUTF];
        acc[0] = fmaf(x0.x, w0, fmaf(x0.y, w1, fmaf(x0.z, w2, fmaf(x0.w, w3, acc[0]))));
        acc[1] = fmaf(x1.x, w0, fmaf(x1.y, w1, fmaf(x1.z, w2, fmaf(x1.w, w3, acc[1]))));
        acc[2] = fmaf(x2.x, w0, fmaf(x2.y, w1, fmaf(x2.z, w2, fmaf(x2.w, w3, acc[2]))));
        acc[3] = fmaf(x3.x, w0, fmaf(x3.y, w1, fmaf(x3.z, w2, fmaf(x3.w, w3, acc[3]))));
    }

    const float a1c = a[c];
    const float a2c = a[64 + c];
    #pragma unroll
    for (int q = 0; q < 4; ++q) {
        float v1 = acc[q] * a1c;
        float v2 = acc[q] * a2c;
        #pragma unroll
        for (int m = 32; m; m >>= 1) {
            v1 += __shfl_xor(v1, m, 64);
            v2 += __shfl_xor(v2, m, 64);
        }
        if (c == 0) {
            const int i = i0 + 4 * w + q;
            U[i]   = __expf((1.0f - ALPHA) * v1);   // exp(0.8 s1)
            E2p[i] = __expf(v2);                    // exp(s2)
            E2n[i] = __expf(ALPHA * v2);            // exp(0.2 s2)
        }
    }

    // A-fragment-swizzled store (verified layout, unchanged)
    const int i   = i0 + 4 * w;
    const int jt  = i >> 5;
    const int sub = (i >> 3) & 3;
    const int e0  = i & 7;
    ushort4 pk;
    pk.x = f2bf(acc[0]); pk.y = f2bf(acc[1]);
    pk.z = f2bf(acc[2]); pk.w = f2bf(acc[3]);
    *(ushort4*)&Asw[((size_t)(c >> 4) * 256 + jt) * 512 + ((c & 15) + 16 * sub) * 8 + e0] = pk;
}

// ---------------------------------------------------------------------------
// Kernel 2: fused masked-softmax attention. Barrier-free, LDS-free, shfl-free.
//   P'_ij = m_ij * max(u_i * E2p_j, E2n_j)   (row factor cancels in softmax)
//   Block = 4 i-tile waves sharing ONE split -> identical A/E2/mask streams
//   across waves (L1 reuse). All operands prefetched one step ahead.
// ---------------------------------------------------------------------------
__global__ __launch_bounds__(256, 3) void k2_attn(
    const unsigned* __restrict__ maskT, const unsigned short* __restrict__ Asw,
    const float* __restrict__ Ug, const float* __restrict__ E2pg,
    const float* __restrict__ E2ng,
    float* __restrict__ Opart, float* __restrict__ lpart)
{
    const int tid   = threadIdx.x;
    const int l     = tid & 63;
    const int w     = tid >> 6;
    const int b     = blockIdx.x;
    const int split = b >> 6;                       // 64 blocks per split
    const int i0    = ((b & 63) * 4 + w) * 32;      // wave-private i-tile
    const int jbase = split * JSPLIT;
    const int jb32  = jbase >> 5;

    const int il  = l & 15;
    const int kg8 = (l >> 4) * 8;

    const float ua = Ug[i0 + il];
    const float ub = Ug[i0 + 16 + il];

    f32x4 a00 = {0,0,0,0}, a01 = {0,0,0,0}, a10 = {0,0,0,0}, a11 = {0,0,0,0};
    f32x4 a20 = {0,0,0,0}, a21 = {0,0,0,0}, a30 = {0,0,0,0}, a31 = {0,0,0,0};
    float rsA = 0.f, rsB = 0.f;

    // ping-pong operand sets
    bf16x8 xA0, xA1, xA2, xA3, yA0, yA1, yA2, yA3;
    float4 xp0, xp1, xn0, xn1, yp0, yp1, yn0, yn1;
    unsigned xmA, xmB, ymA, ymB;

#define LOADSET(T, A0v, A1v, A2v, A3v, P0v, P1v, N0v, N1v, MAv, MBv) do {     \
    const int tt_ = (T) > 15 ? 15 : (T);                                      \
    const unsigned short* An_ = Asw + (size_t)(jb32 + tt_) * 512 + l * 8;     \
    A0v = *(const bf16x8*)(An_);                                              \
    A1v = *(const bf16x8*)(An_ + 131072);                                     \
    A2v = *(const bf16x8*)(An_ + 262144);                                     \
    A3v = *(const bf16x8*)(An_ + 393216);                                     \
    const float* ep_ = E2pg + jbase + tt_ * 32 + kg8;                         \
    const float* en_ = E2ng + jbase + tt_ * 32 + kg8;                         \
    P0v = *(const float4*)(ep_);  P1v = *(const float4*)(ep_ + 4);            \
    N0v = *(const float4*)(en_);  N1v = *(const float4*)(en_ + 4);            \
    MAv = maskT[(size_t)(jb32 + tt_) * NN + i0 + il];                         \
    MBv = maskT[(size_t)(jb32 + tt_) * NN + i0 + 16 + il];                    \
} while (0)

#define SCM(UU, EPV, ENV, BITS, K)                                            \
    ((((BITS) >> (K)) & 1u) ? fmaxf((UU) * (EPV), (ENV)) : 0.f)

#define COMPUTE(A0v, A1v, A2v, A3v, P0v, P1v, N0v, N1v, MAv, MBv) do {        \
    const unsigned bA = (MAv >> kg8) & 0xffu;                                 \
    const unsigned bB = (MBv >> kg8) & 0xffu;                                 \
    const float p0 = SCM(ua, P0v.x, N0v.x, bA, 0);                            \
    const float p1 = SCM(ua, P0v.y, N0v.y, bA, 1);                            \
    const float p2 = SCM(ua, P0v.z, N0v.z, bA, 2);                            \
    const float p3 = SCM(ua, P0v.w, N0v.w, bA, 3);                            \
    const float p4 = SCM(ua, P1v.x, N1v.x, bA, 4);                            \
    const float p5 = SCM(ua, P1v.y, N1v.y, bA, 5);                            \
    const float p6 = SCM(ua, P1v.z, N1v.z, bA, 6);                            \
    const float p7 = SCM(ua, P1v.w, N1v.w, bA, 7);                            \
    const float q0 = SCM(ub, P0v.x, N0v.x, bB, 0);                            \
    const float q1 = SCM(ub, P0v.y, N0v.y, bB, 1);                            \
    const float q2 = SCM(ub, P0v.z, N0v.z, bB, 2);                            \
    const float q3 = SCM(ub, P0v.w, N0v.w, bB, 3);                            \
    const float q4 = SCM(ub, P1v.x, N1v.x, bB, 4);                            \
    const float q5 = SCM(ub, P1v.y, N1v.y, bB, 5);                            \
    const float q6 = SCM(ub, P1v.z, N1v.z, bB, 6);                            \
    const float q7 = SCM(ub, P1v.w, N1v.w, bB, 7);                            \
    rsA += ((p0 + p1) + (p2 + p3)) + ((p4 + p5) + (p6 + p7));                 \
    rsB += ((q0 + q1) + (q2 + q3)) + ((q4 + q5) + (q6 + q7));                 \
    uint4 wa, wb;                                                             \
    asm("v_cvt_pk_bf16_f32 %0, %1, %2" : "=v"(wa.x) : "v"(p0), "v"(p1));      \
    asm("v_cvt_pk_bf16_f32 %0, %1, %2" : "=v"(wa.y) : "v"(p2), "v"(p3));      \
    asm("v_cvt_pk_bf16_f32 %0, %1, %2" : "=v"(wa.z) : "v"(p4), "v"(p5));      \
    asm("v_cvt_pk_bf16_f32 %0, %1, %2" : "=v"(wa.w) : "v"(p6), "v"(p7));      \
    asm("v_cvt_pk_bf16_f32 %0, %1, %2" : "=v"(wb.x) : "v"(q0), "v"(q1));      \
    asm("v_cvt_pk_bf16_f32 %0, %1, %2" : "=v"(wb.y) : "v"(q2), "v"(q3));      \
    asm("v_cvt_pk_bf16_f32 %0, %1, %2" : "=v"(wb.z) : "v"(q4), "v"(q5));      \
    asm("v_cvt_pk_bf16_f32 %0, %1, %2" : "=v"(wb.w) : "v"(q6), "v"(q7));      \
    const bf16x8 BA = __builtin_bit_cast(bf16x8, wa);                         \
    const bf16x8 BB = __builtin_bit_cast(bf16x8, wb);                         \
    a00 = __builtin_amdgcn_mfma_f32_16x16x32_bf16(A0v, BA, a00, 0, 0, 0);     \
    a01 = __builtin_amdgcn_mfma_f32_16x16x32_bf16(A0v, BB, a01, 0, 0, 0);     \
    a10 = __builtin_amdgcn_mfma_f32_16x16x32_bf16(A1v, BA, a10, 0, 0, 0);     \
    a11 = __builtin_amdgcn_mfma_f32_16x16x32_bf16(A1v, BB, a11, 0, 0, 0);     \
    a20 = __builtin_amdgcn_mfma_f32_16x16x32_bf16(A2v, BA, a20, 0, 0, 0);     \
    a21 = __builtin_amdgcn_mfma_f32_16x16x32_bf16(A2v, BB, a21, 0, 0, 0);     \
    a30 = __builtin_amdgcn_mfma_f32_16x16x32_bf16(A3v, BA, a30, 0, 0, 0);     \
    a31 = __builtin_amdgcn_mfma_f32_16x16x32_bf16(A3v, BB, a31, 0, 0, 0);     \
} while (0)

    LOADSET(0, xA0, xA1, xA2, xA3, xp0, xp1, xn0, xn1, xmA, xmB);
    #pragma unroll
    for (int t = 0; t < 16; t += 2) {
        LOADSET(t + 1, yA0, yA1, yA2, yA3, yp0, yp1, yn0, yn1, ymA, ymB);
        COMPUTE(xA0, xA1, xA2, xA3, xp0, xp1, xn0, xn1, xmA, xmB);
        LOADSET(t + 2, xA0, xA1, xA2, xA3, xp0, xp1, xn0, xn1, xmA, xmB);
        COMPUTE(yA0, yA1, yA2, yA3, yp0, yp1, yn0, yn1, ymA, ymB);
    }
#undef LOADSET
#undef SCM
#undef COMPUTE

    // combine the 4 kg-lane-group partial row-sums
    rsA += __shfl_xor(rsA, 16, 64);
    rsA += __shfl_xor(rsA, 32, 64);
    rsB += __shfl_xor(rsB, 16, 64);
    rsB += __shfl_xor(rsB, 32, 64);
    if (l < 16) {
        lpart[(size_t)split * NN + i0 + il]      = rsA;
        lpart[(size_t)split * NN + i0 + 16 + il] = rsB;
    }

    // numerator partials: a<q><h>[r] = out^T[n=q*16+kg*4+r][i=i0+h*16+il]
    const int nn = (l >> 4) * 4;
    float* OA = Opart + ((size_t)split * NN + i0 + il) * OUTF + nn;
    float* OB = OA + (size_t)16 * OUTF;
    *(float4*)(OA)      = *(float4*)&a00;
    *(float4*)(OA + 16) = *(float4*)&a10;
    *(float4*)(OA + 32) = *(float4*)&a20;
    *(float4*)(OA + 48) = *(float4*)&a30;
    *(float4*)(OB)      = *(float4*)&a01;
    *(float4*)(OB + 16) = *(float4*)&a11;
    *(float4*)(OB + 32) = *(float4*)&a21;
    *(float4*)(OB + 48) = *(float4*)&a31;
}

// ---------------------------------------------------------------------------
// Kernel 3: combine the 16 j-split partials and normalize.
// ---------------------------------------------------------------------------
__global__ __launch_bounds__(256) void k3_combine(
    const float* __restrict__ Opart, const float* __restrict__ lpart,
    float* __restrict__ out)
{
    const int f4 = blockIdx.x * 256 + threadIdx.x;   // 0..131071
    const int i  = f4 >> 4;

    float4 r = {0.f, 0.f, 0.f, 0.f};
    float  lsum = 0.f;
    #pragma unroll
    for (int s = 0; s < NSPLIT; ++s) {
        float4 o = *(const float4*)&Opart[(size_t)s * NN * OUTF + (size_t)f4 * 4];
        r.x += o.x; r.y += o.y; r.z += o.z; r.w += o.w;
        lsum += lpart[(size_t)s * NN + i];
    }
    float inv = 1.0f / lsum;
    r.x *= inv; r.y *= inv; r.z *= inv; r.w *= inv;
    *(float4*)&out[(size_t)f4 * 4] = r;
}

extern "C" void kernel_launch(void* const* d_in, const int* in_sizes, int n_in,
                              void* d_out, int out_size, void* d_ws, size_t ws_size,
                              hipStream_t stream) {
    const float* x   = (const float*)d_in[0];
    const int*   adj = (const int*)d_in[1];
    const float* W   = (const float*)d_in[2];
    const float* a   = (const float*)d_in[3];
    float* out = (float*)d_out;

    char* ws = (char*)d_ws;
    unsigned short* Asw = (unsigned short*)ws;                        // 1 MB
    float* U     = (float*)(ws + (1 << 20));                          // 32 KB
    float* E2p   = (float*)(ws + (1 << 20) + 32768);                  // 32 KB
    float* E2n   = (float*)(ws + (1 << 20) + 65536);                  // 32 KB
    float* lpart = (float*)(ws + (1 << 20) + 98304);                  // 512 KB
    unsigned* maskT = (unsigned*)(ws + (1 << 20) + 98304 + 524288);   // 8 MB
    float* Opart = (float*)(ws + (1 << 20) + 98304 + 524288 + (8 << 20)); // 32 MB

    k01_fused<<<GEMM_BLOCKS + 8192, 256, 0, stream>>>(x, adj, W, a, Asw,
                                                      U, E2p, E2n, maskT);
    k2_attn<<<1024, 256, 0, stream>>>(maskT, Asw, U, E2p, E2n, Opart, lpart);
    k3_combine<<<512, 256, 0, stream>>>(Opart, lpart, out);
}